// Round 8
// baseline (163.141 us; speedup 1.0000x reference)
//
#include <hip/hip_runtime.h>

// out[b, c, w, f] = X[b, c, f*HOP + w]
// B=16, C=2, T=262144, WINDOW=1024, HOP=256, NF=1021
#define WINDOW_SZ 1024
#define HOP_SZ    256
#define NFRAMES   1021
#define T_LEN     262144
#define NLINES_TOT 1024

#define CHUNK   256          // frames per pipelined chunk
#define NCHUNK  4
#define SL      260          // staged lines per chunk (CHUNK + 3 k-shift + 1)
#define LSTR    260          // LDS row stride: %32==4 -> 2-way write banks; %4==0 -> b128-aligned
#define TASKS   (SL * 4)     // 1040 stage quad-loads per chunk

typedef float f4  __attribute__((ext_vector_type(4)));
typedef float f4u __attribute__((ext_vector_type(4), aligned(4)));

// Round-5/7 read-once/write-once structure (157.4 reproducible), with ONE
// change: within-block software pipeline (double-buffered 256-line chunks,
// loads for chunk c+1 issued before compute(c)).  Converts the chip-wide
// read-burst -> write-burst alternation into a steady overlapped R/W stream.
__global__ __launch_bounds__(512)
void frame_transpose_kernel(const float* __restrict__ X,
                            float* __restrict__ out) {
    __shared__ float lds[2][16 * LSTR];   // 2 x 16.6 KiB = 33.3 KiB

    const int bid = blockIdx.x;
    const int bc  = bid >> 4;     // 0..31
    const int wg  = bid & 15;     // 0..15
    const int t   = threadIdx.x;

    const float* Xb   = X   + (size_t)bc * T_LEN + wg * 16;
    float*       outb = out + (size_t)(bc * WINDOW_SZ + 16 * wg) * NFRAMES;

    // ---- stage: issue global loads for chunk c into regs (no LDS touch) ----
    auto stage_load = [&](int c, f4* v) {
#pragma unroll
        for (int p = 0; p < 3; ++p) {
            const int idx  = p * 512 + t;          // 0..1535, use < 1040
            const int line = idx >> 2;
            const int sub  = idx & 3;
            const int gl   = c * CHUNK + line;
            v[p] = f4{0.f, 0.f, 0.f, 0.f};
            if (idx < TASKS && gl < NLINES_TOT)
                v[p] = *(const f4*)(Xb + (size_t)gl * HOP_SZ + 4 * sub);
        }
    };
    // ---- write staged regs into LDS buffer (transposed: lds[r][line]) ----
    auto stage_write = [&](float* buf, const f4* v) {
#pragma unroll
        for (int p = 0; p < 3; ++p) {
            const int idx  = p * 512 + t;
            const int line = idx >> 2;
            const int sub  = idx & 3;
            if (idx < TASKS) {
                const int r0 = 4 * sub;
                // bank = (16*(l&3) + (l>>2) + c)%32 across the wave -> 2-way (free)
                buf[(r0 + 0) * LSTR + line] = v[p].x;
                buf[(r0 + 1) * LSTR + line] = v[p].y;
                buf[(r0 + 2) * LSTR + line] = v[p].z;
                buf[(r0 + 3) * LSTR + line] = v[p].w;
            }
        }
    };
    // ---- compute: write f-segment [256c, 256c+256) of all 64 owned rows ----
    auto compute = [&](const float* buf, int c) {
#pragma unroll
        for (int q = 0; q < 8; ++q) {
            const int slot = q * 512 + t;      // 0..4095
            const int k    = slot >> 10;       // 0..3, constant per unrolled q
            const int rem  = slot & 1023;
            const int row  = rem >> 6;         // 0..15, wave-uniform
            const int pos  = rem & 63;         // f4 slot in segment
            const int fb   = c * CHUNK + 4 * pos;
            const float* lrow = buf + row * LSTR + 4 * pos;  // 16B-aligned, conflict-free b128
            float* oaddr = outb + (size_t)(256 * k + row) * NFRAMES + fb;
            if (fb + 3 < NFRAMES) {
                const f4 q0 = *(const f4*)(lrow);
                const f4 q1 = *(const f4*)(lrow + 4);
                f4 o;
                if      (k == 0) o = q0;
                else if (k == 1) o = f4{q0.y, q0.z, q0.w, q1.x};
                else if (k == 2) o = f4{q0.z, q0.w, q1.x, q1.y};
                else             o = f4{q0.w, q1.x, q1.y, q1.z};
                *(f4u*)oaddr = o;              // rows 1021-strided: 4B-aligned vec4
            } else if (fb < NFRAMES) {
                *oaddr = lrow[k];              // f = 1020 tail (c=3, pos=63)
            }
        }
    };

    f4 vA[3], vB[3];

    // prologue: chunk 0
    stage_load(0, vA);
    stage_write(lds[0], vA);
    __syncthreads();

    // c=0
    stage_load(1, vB);            // HBM reads in flight under compute(0)
    compute(lds[0], 0);
    __syncthreads();
    stage_write(lds[1], vB);
    __syncthreads();

    // c=1
    stage_load(2, vA);
    compute(lds[1], 1);
    __syncthreads();
    stage_write(lds[0], vA);
    __syncthreads();

    // c=2
    stage_load(3, vB);
    compute(lds[0], 2);
    __syncthreads();
    stage_write(lds[1], vB);
    __syncthreads();

    // c=3 (epilogue)
    compute(lds[1], 3);
}

extern "C" void kernel_launch(void* const* d_in, const int* in_sizes, int n_in,
                              void* d_out, int out_size, void* d_ws, size_t ws_size,
                              hipStream_t stream) {
    const float* X = (const float*)d_in[0];
    float* out = (float*)d_out;

    dim3 block(512, 1, 1);
    dim3 grid(32 * 16, 1, 1);   // bc (32) x wg (16): 512 blocks, 2 per CU
    frame_transpose_kernel<<<grid, block, 0, stream>>>(X, out);
}

// Round 9
// 159.976 us; speedup vs baseline: 1.0198x; 1.0198x over previous
//
#include <hip/hip_runtime.h>

// out[b, c, w, f] = X[b, c, f*HOP + w]
// B=16, C=2, T=262144, WINDOW=1024, HOP=256, NF=1021
#define WINDOW_SZ 1024
#define HOP_SZ    256
#define NFRAMES   1021
#define T_LEN     262144

#define NLINES 1024   // frames staged per block (1021 used + 3 for the k-shift)
#define LSTR   1028   // LDS row stride: %32==4 -> phase-1 writes 2-way (free)
#define WG_ROWS 16

typedef float f4  __attribute__((ext_vector_type(4)));
typedef float f4u __attribute__((ext_vector_type(4), aligned(4)));

// R7 kernel (157.45, reproduced to 0.02%) + ONE change: chunked XCD swizzle.
// 512 blocks = 8 XCDs x 64: XCD x owns bc in [4x, 4x+4) -> its writes form one
// contiguous 16 MB output window (dense dirty-line packing in its L2 ->
// sequential HBM write bursts), its reads one 4 MB input window.
//  - block (bc, wg) reads bytes [wg*64, wg*64+64) of every 1KB frame in slab bc:
//    read EXACTLY once globally, all full 64B lines.
//  - writes rows w = 256k + 16wg + r: 4 contiguous regions of 65,344 B =
//    exactly 1021 full aligned 64B lines each -> no partial-line RMW.
__global__ __launch_bounds__(512)
void frame_transpose_kernel(const float* __restrict__ X,
                            float* __restrict__ out) {
    __shared__ float lds[WG_ROWS * LSTR];   // 64.25 KiB -> 2 blocks/CU, all 512 resident

    // bijective chunked XCD swizzle (512 % 8 == 0): dispatch round-robins
    // blockIdx%8 across XCDs; remap so XCD x gets contiguous works [64x, 64x+64)
    const int bid  = blockIdx.x;
    const int work = ((bid & 7) << 6) | (bid >> 3);
    const int bc   = work >> 4;     // 0..31 (4 consecutive slabs per XCD)
    const int wg   = work & 15;     // 0..15
    const int t    = threadIdx.x;

    const float* Xbc = X + (size_t)bc * T_LEN + wg * 16;

    // ---- phase 1: 8 x f4 loads/thread, every input line fetched once ----
#pragma unroll
    for (int p = 0; p < 8; ++p) {
        const int idx  = p * 512 + t;     // 0..4095
        const int line = idx >> 2;        // frame 0..1023
        const int sub  = idx & 3;         // f4 within the 64B line
        const f4 v = *(const f4*)(Xbc + line * HOP_SZ + 4 * sub);
        lds[(4 * sub + 0) * LSTR + line] = v.x;
        lds[(4 * sub + 1) * LSTR + line] = v.y;
        lds[(4 * sub + 2) * LSTR + line] = v.z;
        lds[(4 * sub + 3) * LSTR + line] = v.w;
    }

    __syncthreads();

    // ---- phase 2: 4 output regions, all full-line writes ----
#pragma unroll
    for (int k = 0; k < 4; ++k) {
        float* obase = out + (size_t)(bc * WINDOW_SZ + 256 * k + 16 * wg) * NFRAMES;
#pragma unroll
        for (int p = 0; p < 8; ++p) {
            const int slot = p * 512 + t;   // 0..4095 = 16 rows x 256 slots
            const int row  = slot >> 8;     // wave-uniform
            const int pos  = slot & 255;    // f4 slot in the row
            const float* lrow = &lds[row * LSTR + 4 * pos];   // 16B-aligned
            if (pos < 255) {
                const f4 q0 = *(const f4*)(lrow);
                const f4 q1 = *(const f4*)(lrow + 4);
                f4 o;
                if      (k == 0) o = q0;
                else if (k == 1) o = f4{q0.y, q0.z, q0.w, q1.x};
                else if (k == 2) o = f4{q0.z, q0.w, q1.x, q1.y};
                else             o = f4{q0.w, q1.x, q1.y, q1.z};
                *(f4u*)(obase + (size_t)row * NFRAMES + 4 * pos) = o;
            } else {
                obase[(size_t)row * NFRAMES + 1020] = lrow[k];   // f=1020 tail
            }
        }
    }
}

extern "C" void kernel_launch(void* const* d_in, const int* in_sizes, int n_in,
                              void* d_out, int out_size, void* d_ws, size_t ws_size,
                              hipStream_t stream) {
    const float* X = (const float*)d_in[0];
    float* out = (float*)d_out;

    dim3 block(512, 1, 1);
    dim3 grid(32 * 16, 1, 1);   // 512 blocks, 2 per CU, XCD-swizzled in-kernel
    frame_transpose_kernel<<<grid, block, 0, stream>>>(X, out);
}